// Round 1
// baseline (830.988 us; speedup 1.0000x reference)
//
#include <hip/hip_runtime.h>
#include <cstdint>
#include <cstddef>

// ---------------------------------------------------------------------------
// MambaBlock fused pipeline for MI355X (gfx950).
// B=4, S=4096, d=1024, n=16. M = 16384 token rows.
// GEMMs: bf16 MFMA 16x16x32, 128x128 tile, BK=32, global_load_lds(16B).
// ---------------------------------------------------------------------------

typedef short bf16x8 __attribute__((ext_vector_type(8)));
typedef float f32x4 __attribute__((ext_vector_type(4)));

#define GLD16(gp, lp)                                                          \
  __builtin_amdgcn_global_load_lds(                                            \
      (__attribute__((address_space(1))) void*)(gp),                           \
      (__attribute__((address_space(3))) void*)(lp), 16, 0, 0)

static __device__ __forceinline__ ushort f2bf(float f) {
  union { float f; uint32_t u; } c; c.f = f;
  uint32_t r = c.u + 0x7FFFu + ((c.u >> 16) & 1u);
  return (ushort)(r >> 16);
}
static __device__ __forceinline__ float bf2f(ushort u) {
  union { uint32_t u; float f; } c; c.u = ((uint32_t)u) << 16;
  return c.f;
}

// ---------------- LayerNorm: one block per 1024-wide row -------------------
template <int BF16OUT>
__global__ __launch_bounds__(256) void ln_kernel(
    const float* __restrict__ x, const float* __restrict__ w,
    const float* __restrict__ b, void* __restrict__ out) {
  const int row = blockIdx.x;
  const int tid = threadIdx.x;
  const float4 v = ((const float4*)(x + (size_t)row * 1024))[tid];
  float s  = v.x + v.y + v.z + v.w;
  float s2 = v.x * v.x + v.y * v.y + v.z * v.z + v.w * v.w;
#pragma unroll
  for (int off = 32; off > 0; off >>= 1) {
    s  += __shfl_down(s, off);
    s2 += __shfl_down(s2, off);
  }
  __shared__ float red[8];
  const int wv = tid >> 6, ln = tid & 63;
  if (ln == 0) { red[wv] = s; red[4 + wv] = s2; }
  __syncthreads();
  s  = red[0] + red[1] + red[2] + red[3];
  s2 = red[4] + red[5] + red[6] + red[7];
  const float mean = s * (1.f / 1024.f);
  const float var  = s2 * (1.f / 1024.f) - mean * mean;
  const float rstd = rsqrtf(var + 1e-5f);
  const float4 wv4 = ((const float4*)w)[tid];
  const float4 bv4 = ((const float4*)b)[tid];
  const float o0 = (v.x - mean) * rstd * wv4.x + bv4.x;
  const float o1 = (v.y - mean) * rstd * wv4.y + bv4.y;
  const float o2 = (v.z - mean) * rstd * wv4.z + bv4.z;
  const float o3 = (v.w - mean) * rstd * wv4.w + bv4.w;
  if (BF16OUT) {
    ushort4 o; o.x = f2bf(o0); o.y = f2bf(o1); o.z = f2bf(o2); o.w = f2bf(o3);
    ((ushort4*)((ushort*)out + (size_t)row * 1024))[tid] = o;
  } else {
    float4 o; o.x = o0; o.y = o1; o.z = o2; o.w = o3;
    ((float4*)((float*)out + (size_t)row * 1024))[tid] = o;
  }
}

// ------------- depthwise causal conv (k=4) + residual add ------------------
__global__ __launch_bounds__(256) void conv_kernel(
    const float* __restrict__ x, const float* __restrict__ xn,
    const float* __restrict__ cw, const float* __restrict__ cb,
    float* __restrict__ x1) {
  const size_t i = (size_t)blockIdx.x * 256 + threadIdx.x;  // float4 groups
  const int c4 = (int)(i & 255);
  const size_t row = i >> 8;          // b*4096 + t
  const int t = (int)(row & 4095);
  const int c0 = c4 * 4;
  float4 acc = *(const float4*)(cb + c0);
  const float4 w0 = *(const float4*)(cw + (size_t)(c0 + 0) * 4);
  const float4 w1 = *(const float4*)(cw + (size_t)(c0 + 1) * 4);
  const float4 w2 = *(const float4*)(cw + (size_t)(c0 + 2) * 4);
  const float4 w3 = *(const float4*)(cw + (size_t)(c0 + 3) * 4);
  const float4* xnb = (const float4*)xn;
  const size_t rowbase = (row - (size_t)t) << 8;  // (b*4096)*256
#pragma unroll
  for (int j = 0; j < 4; j++) {
    const int tt = t - 3 + j;
    if (tt >= 0) {
      const float4 xv = xnb[rowbase + (size_t)tt * 256 + c4];
      acc.x += xv.x * ((const float*)&w0)[j];
      acc.y += xv.y * ((const float*)&w1)[j];
      acc.z += xv.z * ((const float*)&w2)[j];
      acc.w += xv.w * ((const float*)&w3)[j];
    }
  }
  const float4 xv0 = ((const float4*)x)[i];
  float4 o;
  o.x = xv0.x + acc.x; o.y = xv0.y + acc.y;
  o.z = xv0.z + acc.z; o.w = xv0.w + acc.w;
  ((float4*)x1)[i] = o;
}

// ------------- tiled transpose + fp32->bf16: w (KxN) -> wt (NxK) -----------
__global__ __launch_bounds__(256) void wt_kernel(
    const float* __restrict__ w, ushort* __restrict__ wt, int K, int N) {
  __shared__ float tile[32][33];
  const int tx = threadIdx.x & 31, ty = threadIdx.x >> 5;  // ty 0..7
  const int n0 = blockIdx.x * 32, k0 = blockIdx.y * 32;
#pragma unroll
  for (int j = 0; j < 32; j += 8)
    tile[ty + j][tx] = w[(size_t)(k0 + ty + j) * N + n0 + tx];
  __syncthreads();
#pragma unroll
  for (int j = 0; j < 32; j += 8)
    wt[(size_t)(n0 + ty + j) * K + k0 + tx] = f2bf(tile[tx][ty + j]);
}

// ------------- u = xp @ xp_w + xp_b  (M x 1024) @ (1024 x 16) --------------
__global__ __launch_bounds__(256) void u_kernel(
    const ushort* __restrict__ xp, const float* __restrict__ w,
    const float* __restrict__ wb, float* __restrict__ u) {
  const int tid = threadIdx.x;
  const int r = tid >> 4, n = tid & 15;
  const size_t row = (size_t)blockIdx.x * 16 + r;
  const ushort* xr = xp + row * 1024;
  float acc = wb[n];
  for (int k = 0; k < 1024; k += 8) {
    const uint4 pk = *(const uint4*)(xr + k);
    const ushort* pp = (const ushort*)&pk;
#pragma unroll
    for (int j = 0; j < 8; j++)
      acc += bf2f(pp[j]) * w[(size_t)(k + j) * 16 + n];
  }
  u[row * 16 + n] = acc;
}

// ------------- selective scan: one block per (b,n) sequence ----------------
// h_t = d*h_{t-1} + u_t ; chunked: local scan (16/thread) + Hillis-Steele
// over chunk finals with geometric coefficient d^16 (exact for linear rec.)
__global__ __launch_bounds__(256) void scan_kernel(
    const float* __restrict__ u, const float* __restrict__ A_log,
    float* __restrict__ hs) {
  const int tid = threadIdx.x;
  const int b = blockIdx.x >> 4;
  const int n = blockIdx.x & 15;
  const float d = expf(-expf(A_log[n]));
  const int t0 = tid * 16;
  const float* up = u + ((size_t)b * 4096) * 16 + n;
  float loc[16];
  float h = 0.f;
#pragma unroll
  for (int i = 0; i < 16; i++) {
    h = d * h + up[(size_t)(t0 + i) * 16];
    loc[i] = h;
  }
  __shared__ float sv[256];
  sv[tid] = h;
  __syncthreads();
  float d16 = d * d; d16 *= d16; d16 *= d16; d16 *= d16;  // d^16
  float f = d16;
  for (int off = 1; off < 256; off <<= 1) {
    const float add = (tid >= off) ? sv[tid - off] : 0.f;
    __syncthreads();
    sv[tid] += f * add;
    __syncthreads();
    f *= f;
  }
  const float carry = (tid > 0) ? sv[tid - 1] : 0.f;
  float dp = d;
#pragma unroll
  for (int i = 0; i < 16; i++) {
    const float hg = loc[i] + dp * carry;
    dp *= d;
    // hs layout: (t*4 + b)*16 + n  == GEMM3 row order m' = t*B + b
    hs[((size_t)(t0 + i) * 4 + b) * 16 + n] = hg;
  }
}

// ------------- g[m'] = (hs[m'] @ D) * z[b,t]  -> bf16 ----------------------
__global__ __launch_bounds__(256) void g_kernel(
    const float* __restrict__ hs, const float* __restrict__ Dm,
    const float* __restrict__ z, ushort* __restrict__ g) {
  __shared__ float hsh[256];
  const int tid = threadIdx.x;
  const int r0 = blockIdx.x * 16;
  hsh[tid] = hs[(size_t)r0 * 16 + tid];
  __syncthreads();
  float4 acc[16];
#pragma unroll
  for (int rr = 0; rr < 16; rr++) acc[rr] = make_float4(0.f, 0.f, 0.f, 0.f);
  const float4* Dv = (const float4*)Dm;
#pragma unroll
  for (int n = 0; n < 16; n++) {
    const float4 dv = Dv[(size_t)n * 256 + tid];
#pragma unroll
    for (int rr = 0; rr < 16; rr++) {
      const float h = hsh[rr * 16 + n];
      acc[rr].x += h * dv.x; acc[rr].y += h * dv.y;
      acc[rr].z += h * dv.z; acc[rr].w += h * dv.w;
    }
  }
#pragma unroll
  for (int rr = 0; rr < 16; rr++) {
    const int r = r0 + rr;
    const int b = r & 3, t = r >> 2;
    const float4 zv =
        *(const float4*)(z + ((size_t)b * 4096 + t) * 1024 + tid * 4);
    ushort4 o;
    o.x = f2bf(acc[rr].x * zv.x); o.y = f2bf(acc[rr].y * zv.y);
    o.z = f2bf(acc[rr].z * zv.z); o.w = f2bf(acc[rr].w * zv.w);
    *(ushort4*)(g + (size_t)r * 1024 + tid * 4) = o;
  }
}

// ------------- bf16 MFMA GEMM: C = A(MxK) @ Bt(NxK)^T + bias, epilogues ----
// EPI 0: split N=2048 -> silu->xp bf16 (col<1024), sigmoid->z f32 (col>=1024)
// EPI 1: in-place flat residual add: p0[idx] += v   (x2 = x1 + Y)
// EPI 2: gelu(erf) -> bf16, row stride 2048
// EPI 3: p0[idx] = p1[idx] + v   (final output)
template <int EPI>
__global__ __launch_bounds__(256) void gemm_bt(
    const ushort* __restrict__ A, const ushort* __restrict__ Bt,
    const float* __restrict__ bias, int K, void* __restrict__ p0,
    void* __restrict__ p1) {
  __shared__ ushort As[128 * 32];
  __shared__ ushort Bs[128 * 32];
  const int tid = threadIdx.x;
  const int wave = tid >> 6, lane = tid & 63;
  const int l16 = lane & 15, quad = lane >> 4;
  const int bm0 = blockIdx.x * 128, bn0 = blockIdx.y * 128;
  const int wr = (wave >> 1) * 64, wc = (wave & 1) * 64;
  const int srow = lane >> 2, skel = (lane & 3) << 3;

  const ushort* Ag = A + (size_t)(bm0 + wave * 32 + srow) * K + skel;
  const ushort* Bg = Bt + (size_t)(bn0 + wave * 32 + srow) * K + skel;
  ushort* Al = &As[wave * 32 * 32];
  ushort* Bl = &Bs[wave * 32 * 32];

  f32x4 acc[4][4];
#pragma unroll
  for (int i = 0; i < 4; i++)
#pragma unroll
    for (int j = 0; j < 4; j++) acc[i][j] = (f32x4){0.f, 0.f, 0.f, 0.f};

  for (int k0 = 0; k0 < K; k0 += 32) {
    GLD16(Ag + k0, Al);
    GLD16(Ag + k0 + (size_t)16 * K, Al + 16 * 32);
    GLD16(Bg + k0, Bl);
    GLD16(Bg + k0 + (size_t)16 * K, Bl + 16 * 32);
    __syncthreads();  // drains vmcnt -> LDS writes visible
    bf16x8 aF[4], bF[4];
#pragma unroll
    for (int i = 0; i < 4; i++)
      aF[i] = *(const bf16x8*)&As[(wr + i * 16 + l16) * 32 + quad * 8];
#pragma unroll
    for (int j = 0; j < 4; j++)
      bF[j] = *(const bf16x8*)&Bs[(wc + j * 16 + l16) * 32 + quad * 8];
#pragma unroll
    for (int i = 0; i < 4; i++)
#pragma unroll
      for (int j = 0; j < 4; j++)
        acc[i][j] = __builtin_amdgcn_mfma_f32_16x16x32_bf16(
            aF[i], bF[j], acc[i][j], 0, 0, 0);
    __syncthreads();
  }

#pragma unroll
  for (int i = 0; i < 4; i++) {
    const int row0 = bm0 + wr + i * 16 + quad * 4;
#pragma unroll
    for (int j = 0; j < 4; j++) {
      const int c = bn0 + wc + j * 16 + l16;
      const float bv = bias[c];
#pragma unroll
      for (int r = 0; r < 4; r++) {
        const size_t row = (size_t)(row0 + r);
        const float v = acc[i][j][r] + bv;
        if (EPI == 0) {
          if (c < 1024)
            ((ushort*)p0)[row * 1024 + c] = f2bf(v / (1.f + __expf(-v)));
          else
            ((float*)p1)[row * 1024 + (c - 1024)] = 1.f / (1.f + __expf(-v));
        } else if (EPI == 1) {
          float* io = (float*)p0;
          io[row * 1024 + c] += v;
        } else if (EPI == 2) {
          ((ushort*)p0)[row * 2048 + c] =
              f2bf(0.5f * v * (1.f + erff(v * 0.70710678118654752f)));
        } else {
          ((float*)p0)[row * 1024 + c] =
              ((const float*)p1)[row * 1024 + c] + v;
        }
      }
    }
  }
}

// ---------------------------------------------------------------------------
extern "C" void kernel_launch(void* const* d_in, const int* in_sizes, int n_in,
                              void* d_out, int out_size, void* d_ws,
                              size_t ws_size, hipStream_t stream) {
  const float* x      = (const float*)d_in[0];
  const float* ln1_w  = (const float*)d_in[1];
  const float* ln1_b  = (const float*)d_in[2];
  const float* conv_w = (const float*)d_in[3];
  const float* conv_b = (const float*)d_in[4];
  const float* lns_w  = (const float*)d_in[5];
  const float* lns_b  = (const float*)d_in[6];
  const float* in_w   = (const float*)d_in[7];
  const float* in_b   = (const float*)d_in[8];
  const float* xp_w   = (const float*)d_in[9];
  const float* xp_b   = (const float*)d_in[10];
  const float* A_log  = (const float*)d_in[11];
  const float* Dm     = (const float*)d_in[12];
  const float* out_w  = (const float*)d_in[13];
  const float* out_b  = (const float*)d_in[14];
  const float* ln2_w  = (const float*)d_in[15];
  const float* ln2_b  = (const float*)d_in[16];
  const float* mlp_w1 = (const float*)d_in[17];
  const float* mlp_b1 = (const float*)d_in[18];
  const float* mlp_w2 = (const float*)d_in[19];
  const float* mlp_b2 = (const float*)d_in[20];

  char* wsp = (char*)d_ws;
  size_t off = 0;
  auto alloc = [&](size_t bytes) {
    void* p = wsp + off;
    off += (bytes + 255) & ~(size_t)255;
    return p;
  };
  // 16384 rows x 1024. Aliasing plan (lifetimes disjoint):
  float*  x1    = (float*)alloc(67108864);   // x1 -> x2 (in-place residual)
  float*  xn    = (float*)alloc(67108864);   // ln1 out; later abuf/gbuf
  ushort* abuf  = (ushort*)xn;               // lnS out (dead after GEMM1)
  ushort* gbuf  = (ushort*)xn + 16777216;    // g (written after GEMM1)
  ushort* xpb   = (ushort*)alloc(33554432);  // xp; later h (ln2 out)
  float*  zb    = (float*)alloc(67108864);   // z f32; later h1 bf16
  ushort* h1b   = (ushort*)zb;
  float*  ub    = (float*)alloc(1048576);
  float*  hsb   = (float*)alloc(1048576);
  ushort* in_wT = (ushort*)alloc(4194304);   // 2048 x 1024
  ushort* out_wT= (ushort*)alloc(2097152);   // 1024 x 1024
  ushort* w1T   = (ushort*)alloc(4194304);   // 2048 x 1024
  ushort* w2T   = (ushort*)alloc(4194304);   // 1024 x 2048

  // weight transposes (fp32 -> bf16, KxN -> NxK)
  wt_kernel<<<dim3(64, 32), 256, 0, stream>>>(in_w, in_wT, 1024, 2048);
  wt_kernel<<<dim3(32, 32), 256, 0, stream>>>(out_w, out_wT, 1024, 1024);
  wt_kernel<<<dim3(64, 32), 256, 0, stream>>>(mlp_w1, w1T, 1024, 2048);
  wt_kernel<<<dim3(32, 64), 256, 0, stream>>>(mlp_w2, w2T, 2048, 1024);

  ln_kernel<0><<<16384, 256, 0, stream>>>(x, ln1_w, ln1_b, xn);
  conv_kernel<<<16384, 256, 0, stream>>>(x, xn, conv_w, conv_b, x1);
  ln_kernel<1><<<16384, 256, 0, stream>>>(x1, lns_w, lns_b, abuf);
  gemm_bt<0><<<dim3(128, 16), 256, 0, stream>>>(abuf, in_wT, in_b, 1024,
                                                xpb, zb);
  u_kernel<<<1024, 256, 0, stream>>>(xpb, xp_w, xp_b, ub);
  scan_kernel<<<64, 256, 0, stream>>>(ub, A_log, hsb);
  g_kernel<<<1024, 256, 0, stream>>>(hsb, Dm, zb, gbuf);
  gemm_bt<1><<<dim3(128, 8), 256, 0, stream>>>(gbuf, out_wT, out_b, 1024,
                                               x1, nullptr);
  ln_kernel<1><<<16384, 256, 0, stream>>>(x1, ln2_w, ln2_b, xpb);
  gemm_bt<2><<<dim3(128, 16), 256, 0, stream>>>(xpb, w1T, mlp_b1, 1024,
                                                h1b, nullptr);
  gemm_bt<3><<<dim3(128, 8), 256, 0, stream>>>(h1b, w2T, mlp_b2, 2048,
                                               d_out, x1);
}

// Round 2
// 767.175 us; speedup vs baseline: 1.0832x; 1.0832x over previous
//
#include <hip/hip_runtime.h>
#include <cstdint>
#include <cstddef>

// ---------------------------------------------------------------------------
// MambaBlock fused pipeline for MI355X (gfx950).
// B=4, S=4096, d=1024, n=16. M = 16384 token rows.
// GEMMs: bf16 MFMA 16x16x32, 128x128 tile, BK=32, global_load_lds(16B),
// XOR-swizzled LDS (conflict-free ds_read_b128 fragment reads).
// ---------------------------------------------------------------------------

typedef short bf16x8 __attribute__((ext_vector_type(8)));
typedef float f32x4 __attribute__((ext_vector_type(4)));

#define GLD16(gp, lp)                                                          \
  __builtin_amdgcn_global_load_lds(                                            \
      (__attribute__((address_space(1))) void*)(gp),                           \
      (__attribute__((address_space(3))) void*)(lp), 16, 0, 0)

static __device__ __forceinline__ ushort f2bf(float f) {
  union { float f; uint32_t u; } c; c.f = f;
  uint32_t r = c.u + 0x7FFFu + ((c.u >> 16) & 1u);
  return (ushort)(r >> 16);
}
static __device__ __forceinline__ float bf2f(ushort u) {
  union { uint32_t u; float f; } c; c.u = ((uint32_t)u) << 16;
  return c.f;
}

// ---------------- LayerNorm: one block per 1024-wide row -------------------
template <int BF16OUT>
__global__ __launch_bounds__(256) void ln_kernel(
    const float* __restrict__ x, const float* __restrict__ w,
    const float* __restrict__ b, void* __restrict__ out) {
  const int row = blockIdx.x;
  const int tid = threadIdx.x;
  const float4 v = ((const float4*)(x + (size_t)row * 1024))[tid];
  float s  = v.x + v.y + v.z + v.w;
  float s2 = v.x * v.x + v.y * v.y + v.z * v.z + v.w * v.w;
#pragma unroll
  for (int off = 32; off > 0; off >>= 1) {
    s  += __shfl_down(s, off);
    s2 += __shfl_down(s2, off);
  }
  __shared__ float red[8];
  const int wv = tid >> 6, ln = tid & 63;
  if (ln == 0) { red[wv] = s; red[4 + wv] = s2; }
  __syncthreads();
  s  = red[0] + red[1] + red[2] + red[3];
  s2 = red[4] + red[5] + red[6] + red[7];
  const float mean = s * (1.f / 1024.f);
  const float var  = s2 * (1.f / 1024.f) - mean * mean;
  const float rstd = rsqrtf(var + 1e-5f);
  const float4 wv4 = ((const float4*)w)[tid];
  const float4 bv4 = ((const float4*)b)[tid];
  const float o0 = (v.x - mean) * rstd * wv4.x + bv4.x;
  const float o1 = (v.y - mean) * rstd * wv4.y + bv4.y;
  const float o2 = (v.z - mean) * rstd * wv4.z + bv4.z;
  const float o3 = (v.w - mean) * rstd * wv4.w + bv4.w;
  if (BF16OUT) {
    ushort4 o; o.x = f2bf(o0); o.y = f2bf(o1); o.z = f2bf(o2); o.w = f2bf(o3);
    ((ushort4*)((ushort*)out + (size_t)row * 1024))[tid] = o;
  } else {
    float4 o; o.x = o0; o.y = o1; o.z = o2; o.w = o3;
    ((float4*)((float*)out + (size_t)row * 1024))[tid] = o;
  }
}

// ------------- depthwise causal conv (k=4) + residual add ------------------
__global__ __launch_bounds__(256) void conv_kernel(
    const float* __restrict__ x, const float* __restrict__ xn,
    const float* __restrict__ cw, const float* __restrict__ cb,
    float* __restrict__ x1) {
  const size_t i = (size_t)blockIdx.x * 256 + threadIdx.x;  // float4 groups
  const int c4 = (int)(i & 255);
  const size_t row = i >> 8;          // b*4096 + t
  const int t = (int)(row & 4095);
  const int c0 = c4 * 4;
  float4 acc = *(const float4*)(cb + c0);
  const float4 w0 = *(const float4*)(cw + (size_t)(c0 + 0) * 4);
  const float4 w1 = *(const float4*)(cw + (size_t)(c0 + 1) * 4);
  const float4 w2 = *(const float4*)(cw + (size_t)(c0 + 2) * 4);
  const float4 w3 = *(const float4*)(cw + (size_t)(c0 + 3) * 4);
  const float4* xnb = (const float4*)xn;
  const size_t rowbase = (row - (size_t)t) << 8;  // (b*4096)*256
#pragma unroll
  for (int j = 0; j < 4; j++) {
    const int tt = t - 3 + j;
    if (tt >= 0) {
      const float4 xv = xnb[rowbase + (size_t)tt * 256 + c4];
      acc.x += xv.x * ((const float*)&w0)[j];
      acc.y += xv.y * ((const float*)&w1)[j];
      acc.z += xv.z * ((const float*)&w2)[j];
      acc.w += xv.w * ((const float*)&w3)[j];
    }
  }
  const float4 xv0 = ((const float4*)x)[i];
  float4 o;
  o.x = xv0.x + acc.x; o.y = xv0.y + acc.y;
  o.z = xv0.z + acc.z; o.w = xv0.w + acc.w;
  ((float4*)x1)[i] = o;
}

// ------------- tiled transpose + fp32->bf16: w (KxN) -> wt (NxK) -----------
__global__ __launch_bounds__(256) void wt_kernel(
    const float* __restrict__ w, ushort* __restrict__ wt, int K, int N) {
  __shared__ float tile[32][33];
  const int tx = threadIdx.x & 31, ty = threadIdx.x >> 5;  // ty 0..7
  const int n0 = blockIdx.x * 32, k0 = blockIdx.y * 32;
#pragma unroll
  for (int j = 0; j < 32; j += 8)
    tile[ty + j][tx] = w[(size_t)(k0 + ty + j) * N + n0 + tx];
  __syncthreads();
#pragma unroll
  for (int j = 0; j < 32; j += 8)
    wt[(size_t)(n0 + ty + j) * K + k0 + tx] = f2bf(tile[tx][ty + j]);
}

// ------------- u = xp @ xp_w + xp_b  (M x 1024) @ (1024 x 16) --------------
__global__ __launch_bounds__(256) void u_kernel(
    const ushort* __restrict__ xp, const float* __restrict__ w,
    const float* __restrict__ wb, float* __restrict__ u) {
  const int tid = threadIdx.x;
  const int r = tid >> 4, n = tid & 15;
  const size_t row = (size_t)blockIdx.x * 16 + r;
  const ushort* xr = xp + row * 1024;
  float acc = wb[n];
  for (int k = 0; k < 1024; k += 8) {
    const uint4 pk = *(const uint4*)(xr + k);
    const ushort* pp = (const ushort*)&pk;
#pragma unroll
    for (int j = 0; j < 8; j++)
      acc += bf2f(pp[j]) * w[(size_t)(k + j) * 16 + n];
  }
  u[row * 16 + n] = acc;
}

// ------------- selective scan: one block per (b,n) sequence ----------------
__global__ __launch_bounds__(256) void scan_kernel(
    const float* __restrict__ u, const float* __restrict__ A_log,
    float* __restrict__ hs) {
  const int tid = threadIdx.x;
  const int b = blockIdx.x >> 4;
  const int n = blockIdx.x & 15;
  const float d = expf(-expf(A_log[n]));
  const int t0 = tid * 16;
  const float* up = u + ((size_t)b * 4096) * 16 + n;
  float loc[16];
  float h = 0.f;
#pragma unroll
  for (int i = 0; i < 16; i++) {
    h = d * h + up[(size_t)(t0 + i) * 16];
    loc[i] = h;
  }
  __shared__ float sv[256];
  sv[tid] = h;
  __syncthreads();
  float d16 = d * d; d16 *= d16; d16 *= d16; d16 *= d16;  // d^16
  float f = d16;
  for (int off = 1; off < 256; off <<= 1) {
    const float add = (tid >= off) ? sv[tid - off] : 0.f;
    __syncthreads();
    sv[tid] += f * add;
    __syncthreads();
    f *= f;
  }
  const float carry = (tid > 0) ? sv[tid - 1] : 0.f;
  float dp = d;
#pragma unroll
  for (int i = 0; i < 16; i++) {
    const float hg = loc[i] + dp * carry;
    dp *= d;
    // hs layout: (t*4 + b)*16 + n  == GEMM3 row order m' = t*B + b
    hs[((size_t)(t0 + i) * 4 + b) * 16 + n] = hg;
  }
}

// ------------- g[m'] = (hs[m'] @ D) * z[b,t]  -> bf16 ----------------------
__global__ __launch_bounds__(256) void g_kernel(
    const float* __restrict__ hs, const float* __restrict__ Dm,
    const ushort* __restrict__ z, ushort* __restrict__ g) {
  __shared__ float hsh[256];
  const int tid = threadIdx.x;
  const int r0 = blockIdx.x * 16;
  hsh[tid] = hs[(size_t)r0 * 16 + tid];
  __syncthreads();
  float4 acc[16];
#pragma unroll
  for (int rr = 0; rr < 16; rr++) acc[rr] = make_float4(0.f, 0.f, 0.f, 0.f);
  const float4* Dv = (const float4*)Dm;
#pragma unroll
  for (int n = 0; n < 16; n++) {
    const float4 dv = Dv[(size_t)n * 256 + tid];
#pragma unroll
    for (int rr = 0; rr < 16; rr++) {
      const float h = hsh[rr * 16 + n];
      acc[rr].x += h * dv.x; acc[rr].y += h * dv.y;
      acc[rr].z += h * dv.z; acc[rr].w += h * dv.w;
    }
  }
#pragma unroll
  for (int rr = 0; rr < 16; rr++) {
    const int r = r0 + rr;
    const int b = r & 3, t = r >> 2;
    const ushort4 zv =
        *(const ushort4*)(z + ((size_t)b * 4096 + t) * 1024 + tid * 4);
    ushort4 o;
    o.x = f2bf(acc[rr].x * bf2f(zv.x)); o.y = f2bf(acc[rr].y * bf2f(zv.y));
    o.z = f2bf(acc[rr].z * bf2f(zv.z)); o.w = f2bf(acc[rr].w * bf2f(zv.w));
    *(ushort4*)(g + (size_t)r * 1024 + tid * 4) = o;
  }
}

// ------------- bf16 MFMA GEMM: C = A(MxK) @ Bt(NxK)^T + bias, epilogues ----
// LDS swizzle: 16B block column c of row r stored at slot c ^ ((r>>1)&3).
// Staging achieves this by loading global block (c ^ swz) into slot c
// (global_load_lds dest is fixed at lane*16, so we permute the SOURCE).
// EPI 0: split N=2048 -> silu->xp bf16 (col<1024), sigmoid->z bf16
// EPI 1: in-place flat residual add: p0[idx] += v   (x2 = x1 + Y)
// EPI 2: gelu(erf) -> bf16, row stride 2048
// EPI 3: p0[idx] = p1[idx] + v   (final output)
template <int EPI>
__global__ __launch_bounds__(256) void gemm_bt(
    const ushort* __restrict__ A, const ushort* __restrict__ Bt,
    const float* __restrict__ bias, int K, void* __restrict__ p0,
    void* __restrict__ p1) {
  __shared__ ushort As[128 * 32];
  __shared__ ushort Bs[128 * 32];
  const int tid = threadIdx.x;
  const int wave = tid >> 6, lane = tid & 63;
  const int l16 = lane & 15, quad = lane >> 4;
  const int bm0 = blockIdx.y * 128, bn0 = blockIdx.x * 128;
  const int wr = (wave >> 1) * 64, wc = (wave & 1) * 64;
  const int srow = lane >> 2;
  // staging source block-column swizzle: c' = c ^ ((srow>>1)&3)
  const int skel = (((lane & 3) ^ ((srow >> 1) & 3)) << 3);

  const ushort* Ag = A + (size_t)(bm0 + wave * 32 + srow) * K + skel;
  const ushort* Bg = Bt + (size_t)(bn0 + wave * 32 + srow) * K + skel;
  ushort* Al = &As[wave * 32 * 32];
  ushort* Bl = &Bs[wave * 32 * 32];

  // read-side: row = (multiple of 16) + l16  ->  swz = (l16>>1)&3
  const int rswz = (l16 >> 1) & 3;
  const int coff = ((quad ^ rswz) << 3);

  f32x4 acc[4][4];
#pragma unroll
  for (int i = 0; i < 4; i++)
#pragma unroll
    for (int j = 0; j < 4; j++) acc[i][j] = (f32x4){0.f, 0.f, 0.f, 0.f};

  for (int k0 = 0; k0 < K; k0 += 32) {
    GLD16(Ag + k0, Al);
    GLD16(Ag + k0 + (size_t)16 * K, Al + 16 * 32);
    GLD16(Bg + k0, Bl);
    GLD16(Bg + k0 + (size_t)16 * K, Bl + 16 * 32);
    __syncthreads();  // drains vmcnt -> LDS writes visible
    bf16x8 aF[4], bF[4];
#pragma unroll
    for (int i = 0; i < 4; i++)
      aF[i] = *(const bf16x8*)&As[(wr + i * 16 + l16) * 32 + coff];
#pragma unroll
    for (int j = 0; j < 4; j++)
      bF[j] = *(const bf16x8*)&Bs[(wc + j * 16 + l16) * 32 + coff];
#pragma unroll
    for (int i = 0; i < 4; i++)
#pragma unroll
      for (int j = 0; j < 4; j++)
        acc[i][j] = __builtin_amdgcn_mfma_f32_16x16x32_bf16(
            aF[i], bF[j], acc[i][j], 0, 0, 0);
    __syncthreads();
  }

#pragma unroll
  for (int i = 0; i < 4; i++) {
    const int row0 = bm0 + wr + i * 16 + quad * 4;
#pragma unroll
    for (int j = 0; j < 4; j++) {
      const int c = bn0 + wc + j * 16 + l16;
      const float bv = bias[c];
#pragma unroll
      for (int r = 0; r < 4; r++) {
        const size_t row = (size_t)(row0 + r);
        const float v = acc[i][j][r] + bv;
        if (EPI == 0) {
          if (c < 1024)
            ((ushort*)p0)[row * 1024 + c] = f2bf(v / (1.f + __expf(-v)));
          else
            ((ushort*)p1)[row * 1024 + (c - 1024)] =
                f2bf(1.f / (1.f + __expf(-v)));
        } else if (EPI == 1) {
          float* io = (float*)p0;
          io[row * 1024 + c] += v;
        } else if (EPI == 2) {
          ((ushort*)p0)[row * 2048 + c] =
              f2bf(0.5f * v * (1.f + erff(v * 0.70710678118654752f)));
        } else {
          ((float*)p0)[row * 1024 + c] =
              ((const float*)p1)[row * 1024 + c] + v;
        }
      }
    }
  }
}

// ---------------------------------------------------------------------------
extern "C" void kernel_launch(void* const* d_in, const int* in_sizes, int n_in,
                              void* d_out, int out_size, void* d_ws,
                              size_t ws_size, hipStream_t stream) {
  const float* x      = (const float*)d_in[0];
  const float* ln1_w  = (const float*)d_in[1];
  const float* ln1_b  = (const float*)d_in[2];
  const float* conv_w = (const float*)d_in[3];
  const float* conv_b = (const float*)d_in[4];
  const float* lns_w  = (const float*)d_in[5];
  const float* lns_b  = (const float*)d_in[6];
  const float* in_w   = (const float*)d_in[7];
  const float* in_b   = (const float*)d_in[8];
  const float* xp_w   = (const float*)d_in[9];
  const float* xp_b   = (const float*)d_in[10];
  const float* A_log  = (const float*)d_in[11];
  const float* Dm     = (const float*)d_in[12];
  const float* out_w  = (const float*)d_in[13];
  const float* out_b  = (const float*)d_in[14];
  const float* ln2_w  = (const float*)d_in[15];
  const float* ln2_b  = (const float*)d_in[16];
  const float* mlp_w1 = (const float*)d_in[17];
  const float* mlp_b1 = (const float*)d_in[18];
  const float* mlp_w2 = (const float*)d_in[19];
  const float* mlp_b2 = (const float*)d_in[20];

  char* wsp = (char*)d_ws;
  size_t off = 0;
  auto alloc = [&](size_t bytes) {
    void* p = wsp + off;
    off += (bytes + 255) & ~(size_t)255;
    return p;
  };
  // 16384 rows x 1024. Aliasing plan (lifetimes disjoint):
  float*  x1    = (float*)alloc(67108864);   // x1 -> x2 (in-place residual)
  float*  xn    = (float*)alloc(67108864);   // ln1 out; later abuf/gbuf
  ushort* abuf  = (ushort*)xn;               // lnS out (dead after GEMM1)
  ushort* gbuf  = (ushort*)xn + 16777216;    // g (written after GEMM1)
  ushort* xpb   = (ushort*)alloc(33554432);  // xp; later h (ln2 out)
  ushort* zb    = (ushort*)alloc(67108864);  // z bf16 (32MB); later h1 bf16
  ushort* h1b   = (ushort*)zb;
  float*  ub    = (float*)alloc(1048576);
  float*  hsb   = (float*)alloc(1048576);
  ushort* in_wT = (ushort*)alloc(4194304);   // 2048 x 1024
  ushort* out_wT= (ushort*)alloc(2097152);   // 1024 x 1024
  ushort* w1T   = (ushort*)alloc(4194304);   // 2048 x 1024
  ushort* w2T   = (ushort*)alloc(4194304);   // 1024 x 2048

  // weight transposes (fp32 -> bf16, KxN -> NxK)
  wt_kernel<<<dim3(64, 32), 256, 0, stream>>>(in_w, in_wT, 1024, 2048);
  wt_kernel<<<dim3(32, 32), 256, 0, stream>>>(out_w, out_wT, 1024, 1024);
  wt_kernel<<<dim3(64, 32), 256, 0, stream>>>(mlp_w1, w1T, 1024, 2048);
  wt_kernel<<<dim3(32, 64), 256, 0, stream>>>(mlp_w2, w2T, 2048, 1024);

  ln_kernel<0><<<16384, 256, 0, stream>>>(x, ln1_w, ln1_b, xn);
  conv_kernel<<<16384, 256, 0, stream>>>(x, xn, conv_w, conv_b, x1);
  ln_kernel<1><<<16384, 256, 0, stream>>>(x1, lns_w, lns_b, abuf);
  gemm_bt<0><<<dim3(16, 128), 256, 0, stream>>>(abuf, in_wT, in_b, 1024,
                                                xpb, zb);
  u_kernel<<<1024, 256, 0, stream>>>(xpb, xp_w, xp_b, ub);
  scan_kernel<<<64, 256, 0, stream>>>(ub, A_log, hsb);
  g_kernel<<<1024, 256, 0, stream>>>(hsb, Dm, zb, gbuf);
  gemm_bt<1><<<dim3(8, 128), 256, 0, stream>>>(gbuf, out_wT, out_b, 1024,
                                               x1, nullptr);
  ln_kernel<1><<<16384, 256, 0, stream>>>(x1, ln2_w, ln2_b, xpb);
  gemm_bt<2><<<dim3(16, 128), 256, 0, stream>>>(xpb, w1T, mlp_b1, 1024,
                                                h1b, nullptr);
  gemm_bt<3><<<dim3(8, 128), 256, 0, stream>>>(h1b, w2T, mlp_b2, 2048,
                                               d_out, x1);
}

// Round 3
// 688.704 us; speedup vs baseline: 1.2066x; 1.1139x over previous
//
#include <hip/hip_runtime.h>
#include <cstdint>
#include <cstddef>

// ---------------------------------------------------------------------------
// MambaBlock fused pipeline for MI355X (gfx950).
// B=4, S=4096, d=1024, n=16. M = 16384 token rows.
// GEMMs: bf16 MFMA 16x16x32, 128x128 tile, BK=64, global_load_lds(16B),
// XOR-swizzled LDS (blk ^ (row&7)) -> conflict-free ds_read_b128.
// Front-end (ln1 + causal conv + residual + lnS) fused into one kernel.
// ---------------------------------------------------------------------------

typedef short bf16x8 __attribute__((ext_vector_type(8)));
typedef float f32x4 __attribute__((ext_vector_type(4)));

#define GLD16(gp, lp)                                                          \
  __builtin_amdgcn_global_load_lds(                                            \
      (__attribute__((address_space(1))) void*)(gp),                           \
      (__attribute__((address_space(3))) void*)(lp), 16, 0, 0)

static __device__ __forceinline__ ushort f2bf(float f) {
  union { float f; uint32_t u; } c; c.f = f;
  uint32_t r = c.u + 0x7FFFu + ((c.u >> 16) & 1u);
  return (ushort)(r >> 16);
}
static __device__ __forceinline__ float bf2f(ushort u) {
  union { uint32_t u; float f; } c; c.u = ((uint32_t)u) << 16;
  return c.f;
}

// ---------------- LayerNorm: one block per 1024-wide row -------------------
template <int BF16OUT>
__global__ __launch_bounds__(256) void ln_kernel(
    const float* __restrict__ x, const float* __restrict__ w,
    const float* __restrict__ b, void* __restrict__ out) {
  const int row = blockIdx.x;
  const int tid = threadIdx.x;
  const float4 v = ((const float4*)(x + (size_t)row * 1024))[tid];
  float s  = v.x + v.y + v.z + v.w;
  float s2 = v.x * v.x + v.y * v.y + v.z * v.z + v.w * v.w;
#pragma unroll
  for (int off = 32; off > 0; off >>= 1) {
    s  += __shfl_down(s, off);
    s2 += __shfl_down(s2, off);
  }
  __shared__ float red[8];
  const int wv = tid >> 6, ln = tid & 63;
  if (ln == 0) { red[wv] = s; red[4 + wv] = s2; }
  __syncthreads();
  s  = red[0] + red[1] + red[2] + red[3];
  s2 = red[4] + red[5] + red[6] + red[7];
  const float mean = s * (1.f / 1024.f);
  const float var  = s2 * (1.f / 1024.f) - mean * mean;
  const float rstd = rsqrtf(var + 1e-5f);
  const float4 wv4 = ((const float4*)w)[tid];
  const float4 bv4 = ((const float4*)b)[tid];
  const float o0 = (v.x - mean) * rstd * wv4.x + bv4.x;
  const float o1 = (v.y - mean) * rstd * wv4.y + bv4.y;
  const float o2 = (v.z - mean) * rstd * wv4.z + bv4.z;
  const float o3 = (v.w - mean) * rstd * wv4.w + bv4.w;
  if (BF16OUT) {
    ushort4 o; o.x = f2bf(o0); o.y = f2bf(o1); o.z = f2bf(o2); o.w = f2bf(o3);
    ((ushort4*)((ushort*)out + (size_t)row * 1024))[tid] = o;
  } else {
    float4 o; o.x = o0; o.y = o1; o.z = o2; o.w = o3;
    ((float4*)((float*)out + (size_t)row * 1024))[tid] = o;
  }
}

// ---- fused: ln1(x[t-3..t]) -> depthwise conv(k=4) + x residual -> x1 ------
// ----        then lnS(x1) -> abuf (bf16).  One block per token row. --------
__global__ __launch_bounds__(256) void lnconv_kernel(
    const float* __restrict__ x, const float* __restrict__ ln1w,
    const float* __restrict__ ln1b, const float* __restrict__ cw,
    const float* __restrict__ cb, const float* __restrict__ lnsw,
    const float* __restrict__ lnsb, float* __restrict__ x1,
    ushort* __restrict__ abuf) {
  const int row = blockIdx.x;           // b*4096 + t
  const int t = row & 4095;
  const int tid = threadIdx.x;
  const int wv = tid >> 6, ln = tid & 63;
  const float4* x4 = (const float4*)x;
  float4 xr[4];
  float s[4], q[4];
#pragma unroll
  for (int j = 0; j < 4; j++) {
    const int tt = t - 3 + j;
    if (tt >= 0)
      xr[j] = x4[(size_t)(row - 3 + j) * 256 + tid];
    else
      xr[j] = make_float4(0.f, 0.f, 0.f, 0.f);
    s[j] = xr[j].x + xr[j].y + xr[j].z + xr[j].w;
    q[j] = xr[j].x * xr[j].x + xr[j].y * xr[j].y + xr[j].z * xr[j].z +
           xr[j].w * xr[j].w;
  }
#pragma unroll
  for (int off = 32; off > 0; off >>= 1) {
#pragma unroll
    for (int j = 0; j < 4; j++) {
      s[j] += __shfl_down(s[j], off);
      q[j] += __shfl_down(q[j], off);
    }
  }
  __shared__ float red[4][8];
  __shared__ float red2[8];
  if (ln == 0) {
#pragma unroll
    for (int j = 0; j < 4; j++) { red[wv][j] = s[j]; red[wv][4 + j] = q[j]; }
  }
  __syncthreads();
  float4 wv4 = ((const float4*)ln1w)[tid];
  float4 bv4 = ((const float4*)ln1b)[tid];
  const int c0 = tid * 4;
  float4 acc = *(const float4*)(cb + c0);
  const float4 w0 = *(const float4*)(cw + (size_t)(c0 + 0) * 4);
  const float4 w1 = *(const float4*)(cw + (size_t)(c0 + 1) * 4);
  const float4 w2 = *(const float4*)(cw + (size_t)(c0 + 2) * 4);
  const float4 w3 = *(const float4*)(cw + (size_t)(c0 + 3) * 4);
#pragma unroll
  for (int j = 0; j < 4; j++) {
    if (t - 3 + j >= 0) {
      const float sm = red[0][j] + red[1][j] + red[2][j] + red[3][j];
      const float sq = red[0][4 + j] + red[1][4 + j] + red[2][4 + j] +
                       red[3][4 + j];
      const float mean = sm * (1.f / 1024.f);
      const float var  = sq * (1.f / 1024.f) - mean * mean;
      const float rstd = rsqrtf(var + 1e-5f);
      const float lx = (xr[j].x - mean) * rstd * wv4.x + bv4.x;
      const float ly = (xr[j].y - mean) * rstd * wv4.y + bv4.y;
      const float lz = (xr[j].z - mean) * rstd * wv4.z + bv4.z;
      const float lw = (xr[j].w - mean) * rstd * wv4.w + bv4.w;
      acc.x += lx * ((const float*)&w0)[j];
      acc.y += ly * ((const float*)&w1)[j];
      acc.z += lz * ((const float*)&w2)[j];
      acc.w += lw * ((const float*)&w3)[j];
    }
  }
  float4 o;
  o.x = xr[3].x + acc.x; o.y = xr[3].y + acc.y;
  o.z = xr[3].z + acc.z; o.w = xr[3].w + acc.w;
  ((float4*)x1)[(size_t)row * 256 + tid] = o;
  // ---- lnS on o ----
  float s2 = o.x + o.y + o.z + o.w;
  float q2 = o.x * o.x + o.y * o.y + o.z * o.z + o.w * o.w;
#pragma unroll
  for (int off = 32; off > 0; off >>= 1) {
    s2 += __shfl_down(s2, off);
    q2 += __shfl_down(q2, off);
  }
  if (ln == 0) { red2[wv] = s2; red2[4 + wv] = q2; }
  __syncthreads();
  const float sm = red2[0] + red2[1] + red2[2] + red2[3];
  const float sq = red2[4] + red2[5] + red2[6] + red2[7];
  const float mean = sm * (1.f / 1024.f);
  const float var  = sq * (1.f / 1024.f) - mean * mean;
  const float rstd = rsqrtf(var + 1e-5f);
  wv4 = ((const float4*)lnsw)[tid];
  bv4 = ((const float4*)lnsb)[tid];
  ushort4 a;
  a.x = f2bf((o.x - mean) * rstd * wv4.x + bv4.x);
  a.y = f2bf((o.y - mean) * rstd * wv4.y + bv4.y);
  a.z = f2bf((o.z - mean) * rstd * wv4.z + bv4.z);
  a.w = f2bf((o.w - mean) * rstd * wv4.w + bv4.w);
  ((ushort4*)(abuf + (size_t)row * 1024))[tid] = a;
}

// ------- merged tiled transpose + fp32->bf16 for all 4 weights -------------
__global__ __launch_bounds__(256) void wt_all_kernel(
    const float* __restrict__ in_w, const float* __restrict__ out_w,
    const float* __restrict__ w1, const float* __restrict__ w2,
    ushort* __restrict__ in_wT, ushort* __restrict__ out_wT,
    ushort* __restrict__ w1T, ushort* __restrict__ w2T) {
  __shared__ float tile[32][33];
  const int idx = blockIdx.x;
  const float* src; ushort* dst; int K, N, n0, k0;
  if (idx < 2048) {
    src = in_w; dst = in_wT; K = 1024; N = 2048;
    n0 = (idx & 63) * 32; k0 = (idx >> 6) * 32;
  } else if (idx < 3072) {
    const int r = idx - 2048;
    src = out_w; dst = out_wT; K = 1024; N = 1024;
    n0 = (r & 31) * 32; k0 = (r >> 5) * 32;
  } else if (idx < 5120) {
    const int r = idx - 3072;
    src = w1; dst = w1T; K = 1024; N = 2048;
    n0 = (r & 63) * 32; k0 = (r >> 6) * 32;
  } else {
    const int r = idx - 5120;
    src = w2; dst = w2T; K = 2048; N = 1024;
    n0 = (r & 31) * 32; k0 = (r >> 5) * 32;
  }
  const int tx = threadIdx.x & 31, ty = threadIdx.x >> 5;
#pragma unroll
  for (int j = 0; j < 32; j += 8)
    tile[ty + j][tx] = src[(size_t)(k0 + ty + j) * N + n0 + tx];
  __syncthreads();
#pragma unroll
  for (int j = 0; j < 32; j += 8)
    dst[(size_t)(n0 + ty + j) * K + k0 + tx] = f2bf(tile[tx][ty + j]);
}

// ------------- u = xp @ xp_w + xp_b via MFMA (N=16) ------------------------
__global__ __launch_bounds__(256) void u_mfma_kernel(
    const ushort* __restrict__ xp, const float* __restrict__ xpw,
    const float* __restrict__ xpb, float* __restrict__ u) {
  __shared__ ushort Ws[16 * 1024];  // W^T bf16, 16B-block swizzled
  __shared__ ushort As[64 * 64];
  const int tid = threadIdx.x;
  const int wave = tid >> 6, lane = tid & 63;
  const int l16 = lane & 15, quad = lane >> 4;
  for (int e = tid; e < 16384; e += 256) {
    const int n = e & 15, k = e >> 4;
    Ws[n * 1024 + (((k >> 3) ^ (n & 7)) << 3) + (k & 7)] =
        f2bf(xpw[(size_t)k * 16 + n]);
  }
  const int bm0 = blockIdx.x * 64;
  const int srow = lane >> 3, sblk = (lane & 7) ^ (srow & 7);
  const ushort* Ag = xp + (size_t)(bm0 + wave * 16 + srow) * 1024 + sblk * 8;
  ushort* Al = &As[wave * 16 * 64];
  const int rsw = l16 & 7;
  f32x4 acc = (f32x4){0.f, 0.f, 0.f, 0.f};
  __syncthreads();
  for (int k0 = 0; k0 < 1024; k0 += 64) {
    GLD16(Ag + k0, Al);
    GLD16(Ag + k0 + (size_t)8 * 1024, Al + 512);
    __syncthreads();
#pragma unroll
    for (int kh = 0; kh < 2; kh++) {
      const bf16x8 aF = *(const bf16x8*)
          &As[(wave * 16 + l16) * 64 + (((kh * 4 + quad) ^ rsw) << 3)];
      const bf16x8 bF = *(const bf16x8*)
          &Ws[l16 * 1024 + ((((k0 >> 3) + kh * 4 + quad) ^ rsw) << 3)];
      acc = __builtin_amdgcn_mfma_f32_16x16x32_bf16(aF, bF, acc, 0, 0, 0);
    }
    __syncthreads();
  }
  const float bv = xpb[l16];
#pragma unroll
  for (int r = 0; r < 4; r++) {
    const int row = bm0 + wave * 16 + quad * 4 + r;
    u[(size_t)row * 16 + l16] = acc[r] + bv;
  }
}

// ------------- selective scan: one block per (b,n) sequence ----------------
__global__ __launch_bounds__(256) void scan_kernel(
    const float* __restrict__ u, const float* __restrict__ A_log,
    float* __restrict__ hs) {
  const int tid = threadIdx.x;
  const int b = blockIdx.x >> 4;
  const int n = blockIdx.x & 15;
  const float d = expf(-expf(A_log[n]));
  const int t0 = tid * 16;
  const float* up = u + ((size_t)b * 4096) * 16 + n;
  float loc[16];
  float h = 0.f;
#pragma unroll
  for (int i = 0; i < 16; i++) {
    h = d * h + up[(size_t)(t0 + i) * 16];
    loc[i] = h;
  }
  __shared__ float sv[256];
  sv[tid] = h;
  __syncthreads();
  float d16 = d * d; d16 *= d16; d16 *= d16; d16 *= d16;  // d^16
  float f = d16;
  for (int off = 1; off < 256; off <<= 1) {
    const float add = (tid >= off) ? sv[tid - off] : 0.f;
    __syncthreads();
    sv[tid] += f * add;
    __syncthreads();
    f *= f;
  }
  const float carry = (tid > 0) ? sv[tid - 1] : 0.f;
  float dp = d;
#pragma unroll
  for (int i = 0; i < 16; i++) {
    const float hg = loc[i] + dp * carry;
    dp *= d;
    // hs layout: (t*4 + b)*16 + n  == GEMM3 row order m' = t*B + b
    hs[((size_t)(t0 + i) * 4 + b) * 16 + n] = hg;
  }
}

// ------------- g[m'] = (hs[m'] @ D) * z[b,t]  -> bf16 ----------------------
__global__ __launch_bounds__(256) void g_kernel(
    const float* __restrict__ hs, const float* __restrict__ Dm,
    const ushort* __restrict__ z, ushort* __restrict__ g) {
  __shared__ float hsh[256];
  const int tid = threadIdx.x;
  const int r0 = blockIdx.x * 16;
  hsh[tid] = hs[(size_t)r0 * 16 + tid];
  __syncthreads();
  float4 acc[16];
#pragma unroll
  for (int rr = 0; rr < 16; rr++) acc[rr] = make_float4(0.f, 0.f, 0.f, 0.f);
  const float4* Dv = (const float4*)Dm;
#pragma unroll
  for (int n = 0; n < 16; n++) {
    const float4 dv = Dv[(size_t)n * 256 + tid];
#pragma unroll
    for (int rr = 0; rr < 16; rr++) {
      const float h = hsh[rr * 16 + n];
      acc[rr].x += h * dv.x; acc[rr].y += h * dv.y;
      acc[rr].z += h * dv.z; acc[rr].w += h * dv.w;
    }
  }
#pragma unroll
  for (int rr = 0; rr < 16; rr++) {
    const int r = r0 + rr;
    const int b = r & 3, t = r >> 2;
    const ushort4 zv =
        *(const ushort4*)(z + ((size_t)b * 4096 + t) * 1024 + tid * 4);
    ushort4 o;
    o.x = f2bf(acc[rr].x * bf2f(zv.x)); o.y = f2bf(acc[rr].y * bf2f(zv.y));
    o.z = f2bf(acc[rr].z * bf2f(zv.z)); o.w = f2bf(acc[rr].w * bf2f(zv.w));
    *(ushort4*)(g + (size_t)r * 1024 + tid * 4) = o;
  }
}

// ------------- bf16 MFMA GEMM: C = A(MxK) @ Bt(NxK)^T + bias, epilogues ----
// BK=64. LDS 16B-block c of row r stored at slot c ^ (r&7); staging permutes
// the global SOURCE (global_load_lds dest is fixed at lane*16).
// EPI 0: split N=2048 -> silu->xp bf16 (col<1024), sigmoid->z bf16
// EPI 1: in-place flat residual add: p0[idx] += v   (x2 = x1 + Y)
// EPI 2: gelu(erf) -> bf16, row stride 2048
// EPI 3: p0[idx] = p1[idx] + v   (final output)
template <int EPI>
__global__ __launch_bounds__(256) void gemm_bt(
    const ushort* __restrict__ A, const ushort* __restrict__ Bt,
    const float* __restrict__ bias, int K, void* __restrict__ p0,
    void* __restrict__ p1) {
  __shared__ ushort As[128 * 64];
  __shared__ ushort Bs[128 * 64];
  const int tid = threadIdx.x;
  const int wave = tid >> 6, lane = tid & 63;
  const int l16 = lane & 15, quad = lane >> 4;
  const int bm0 = blockIdx.x * 128, bn0 = blockIdx.y * 128;
  const int wr = (wave >> 1) * 64, wc = (wave & 1) * 64;
  const int srow = lane >> 3;                   // 0..7
  const int sblk = (lane & 7) ^ (srow & 7);     // swizzled src 16B block

  const ushort* Ag = A + (size_t)(bm0 + wave * 32 + srow) * K + sblk * 8;
  const ushort* Bg = Bt + (size_t)(bn0 + wave * 32 + srow) * K + sblk * 8;
  ushort* Al = &As[wave * 32 * 64];
  ushort* Bl = &Bs[wave * 32 * 64];
  const int rsw = l16 & 7;

  f32x4 acc[4][4];
#pragma unroll
  for (int i = 0; i < 4; i++)
#pragma unroll
    for (int j = 0; j < 4; j++) acc[i][j] = (f32x4){0.f, 0.f, 0.f, 0.f};

  for (int k0 = 0; k0 < K; k0 += 64) {
#pragma unroll
    for (int i = 0; i < 4; i++) {
      GLD16(Ag + (size_t)(i * 8) * K + k0, Al + i * 512);
      GLD16(Bg + (size_t)(i * 8) * K + k0, Bl + i * 512);
    }
    __syncthreads();  // drains vmcnt -> LDS writes visible
#pragma unroll
    for (int kh = 0; kh < 2; kh++) {
      const int c8 = ((kh * 4 + quad) ^ rsw) << 3;
      bf16x8 aF[4], bF[4];
#pragma unroll
      for (int i = 0; i < 4; i++)
        aF[i] = *(const bf16x8*)&As[(wr + i * 16 + l16) * 64 + c8];
#pragma unroll
      for (int j = 0; j < 4; j++)
        bF[j] = *(const bf16x8*)&Bs[(wc + j * 16 + l16) * 64 + c8];
#pragma unroll
      for (int i = 0; i < 4; i++)
#pragma unroll
        for (int j = 0; j < 4; j++)
          acc[i][j] = __builtin_amdgcn_mfma_f32_16x16x32_bf16(
              aF[i], bF[j], acc[i][j], 0, 0, 0);
    }
    __syncthreads();
  }

#pragma unroll
  for (int i = 0; i < 4; i++) {
    const int row0 = bm0 + wr + i * 16 + quad * 4;
#pragma unroll
    for (int j = 0; j < 4; j++) {
      const int c = bn0 + wc + j * 16 + l16;
      const float bv = bias[c];
#pragma unroll
      for (int r = 0; r < 4; r++) {
        const size_t row = (size_t)(row0 + r);
        const float v = acc[i][j][r] + bv;
        if (EPI == 0) {
          if (c < 1024)
            ((ushort*)p0)[row * 1024 + c] = f2bf(v / (1.f + __expf(-v)));
          else
            ((ushort*)p1)[row * 1024 + (c - 1024)] =
                f2bf(1.f / (1.f + __expf(-v)));
        } else if (EPI == 1) {
          float* io = (float*)p0;
          io[row * 1024 + c] += v;
        } else if (EPI == 2) {
          ((ushort*)p0)[row * 2048 + c] =
              f2bf(0.5f * v * (1.f + erff(v * 0.70710678118654752f)));
        } else {
          ((float*)p0)[row * 1024 + c] =
              ((const float*)p1)[row * 1024 + c] + v;
        }
      }
    }
  }
}

// ---------------------------------------------------------------------------
extern "C" void kernel_launch(void* const* d_in, const int* in_sizes, int n_in,
                              void* d_out, int out_size, void* d_ws,
                              size_t ws_size, hipStream_t stream) {
  const float* x      = (const float*)d_in[0];
  const float* ln1_w  = (const float*)d_in[1];
  const float* ln1_b  = (const float*)d_in[2];
  const float* conv_w = (const float*)d_in[3];
  const float* conv_b = (const float*)d_in[4];
  const float* lns_w  = (const float*)d_in[5];
  const float* lns_b  = (const float*)d_in[6];
  const float* in_w   = (const float*)d_in[7];
  const float* in_b   = (const float*)d_in[8];
  const float* xp_w   = (const float*)d_in[9];
  const float* xp_b   = (const float*)d_in[10];
  const float* A_log  = (const float*)d_in[11];
  const float* Dm     = (const float*)d_in[12];
  const float* out_w  = (const float*)d_in[13];
  const float* out_b  = (const float*)d_in[14];
  const float* ln2_w  = (const float*)d_in[15];
  const float* ln2_b  = (const float*)d_in[16];
  const float* mlp_w1 = (const float*)d_in[17];
  const float* mlp_b1 = (const float*)d_in[18];
  const float* mlp_w2 = (const float*)d_in[19];
  const float* mlp_b2 = (const float*)d_in[20];

  char* wsp = (char*)d_ws;
  size_t off = 0;
  auto alloc = [&](size_t bytes) {
    void* p = wsp + off;
    off += (bytes + 255) & ~(size_t)255;
    return p;
  };
  // 16384 rows x 1024. Aliasing plan (lifetimes disjoint):
  float*  x1    = (float*)alloc(67108864);   // x1 -> x2 (in-place residual)
  ushort* abuf  = (ushort*)alloc(67108864);  // lnS out (dead after GEMM1)
  ushort* gbuf  = abuf + 16777216;           // g (written after GEMM1)
  ushort* xpb   = (ushort*)alloc(33554432);  // xp; later h (ln2 out)
  ushort* zb    = (ushort*)alloc(67108864);  // z bf16 (32MB); later h1 bf16
  ushort* h1b   = (ushort*)zb;
  float*  ub    = (float*)alloc(1048576);
  float*  hsb   = (float*)alloc(1048576);
  ushort* in_wT = (ushort*)alloc(4194304);   // 2048 x 1024
  ushort* out_wT= (ushort*)alloc(2097152);   // 1024 x 1024
  ushort* w1T   = (ushort*)alloc(4194304);   // 2048 x 1024
  ushort* w2T   = (ushort*)alloc(4194304);   // 1024 x 2048

  wt_all_kernel<<<7168, 256, 0, stream>>>(in_w, out_w, mlp_w1, mlp_w2,
                                          in_wT, out_wT, w1T, w2T);
  lnconv_kernel<<<16384, 256, 0, stream>>>(x, ln1_w, ln1_b, conv_w, conv_b,
                                           lns_w, lns_b, x1, abuf);
  gemm_bt<0><<<dim3(128, 16), 256, 0, stream>>>(abuf, in_wT, in_b, 1024,
                                                xpb, zb);
  u_mfma_kernel<<<256, 256, 0, stream>>>(xpb, xp_w, xp_b, ub);
  scan_kernel<<<64, 256, 0, stream>>>(ub, A_log, hsb);
  g_kernel<<<1024, 256, 0, stream>>>(hsb, Dm, zb, gbuf);
  gemm_bt<1><<<dim3(128, 8), 256, 0, stream>>>(gbuf, out_wT, out_b, 1024,
                                               x1, nullptr);
  ln_kernel<1><<<16384, 256, 0, stream>>>(x1, ln2_w, ln2_b, xpb);
  gemm_bt<2><<<dim3(128, 16), 256, 0, stream>>>(xpb, w1T, mlp_b1, 1024,
                                                h1b, nullptr);
  gemm_bt<3><<<dim3(128, 8), 256, 0, stream>>>(h1b, w2T, mlp_b2, 2048,
                                               d_out, x1);
}